// Round 7
// baseline (657.144 us; speedup 1.0000x reference)
//
#include <hip/hip_runtime.h>
#include <stdint.h>

#define TOK 4096
#define HD 2048
#define ID 1408
#define NE 8
#define GMAX 5120
#define NTILES 40

typedef unsigned short u16;
typedef unsigned int u32;
typedef __attribute__((ext_vector_type(8))) short bf16x8;
typedef __attribute__((ext_vector_type(4))) float f32x4;

__device__ inline u16 f2bf(float f) {
  u32 u = __builtin_bit_cast(u32, f);
  u += 0x7fff + ((u >> 16) & 1);   // RNE
  return (u16)(u >> 16);
}
__device__ inline u32 pk2(float a, float b) {
  return (u32)f2bf(a) | ((u32)f2bf(b) << 16);
}
__device__ inline uint4 pk8(const float4& a, const float4& b) {
  uint4 r;
  r.x = pk2(a.x, a.y); r.y = pk2(a.z, a.w);
  r.z = pk2(b.x, b.y); r.w = pk2(b.z, b.w);
  return r;
}
__device__ inline void gload_lds16(void* lds, const void* g) {
  __builtin_amdgcn_global_load_lds(
      (const __attribute__((address_space(1))) u32*)g,
      (__attribute__((address_space(3))) u32*)lds, 16, 0, 0);
}

__global__ void k_init(int* counts, int* cursors) {
  if (threadIdx.x < NE) { counts[threadIdx.x] = 0; cursors[threadIdx.x] = 0; }
}

__global__ void k_router(const float* __restrict__ x, const float* __restrict__ rw,
                         int* __restrict__ counts, int* __restrict__ expert_t,
                         float* __restrict__ weight_t) {
  const int lane = threadIdx.x & 63;
  const int t = blockIdx.x * 4 + (threadIdx.x >> 6);
  const float4* xr = (const float4*)(x + (size_t)t * HD);
  float acc[NE];
#pragma unroll
  for (int e = 0; e < NE; ++e) acc[e] = 0.f;
#pragma unroll
  for (int it = 0; it < HD / 256; ++it) {
    float4 xv = xr[it * 64 + lane];
#pragma unroll
    for (int e = 0; e < NE; ++e) {
      float4 wv = ((const float4*)(rw + e * HD))[it * 64 + lane];
      acc[e] += xv.x * wv.x + xv.y * wv.y + xv.z * wv.z + xv.w * wv.w;
    }
  }
#pragma unroll
  for (int e = 0; e < NE; ++e) {
#pragma unroll
    for (int off = 32; off > 0; off >>= 1) acc[e] += __shfl_xor(acc[e], off, 64);
  }
  if (lane == 0) {
    float v0 = -1e30f, v1 = -1e30f; int ie = 0;
#pragma unroll
    for (int e = 0; e < NE; ++e) {
      float v = acc[e];
      if (v > v0) { v1 = v0; v0 = v; ie = e; }
      else if (v > v1) { v1 = v; }
    }
    expert_t[t] = ie;
    weight_t[t] = 1.f / (1.f + __expf(v1 - v0));
    atomicAdd(counts + ie, 1);
  }
}

__global__ void k_scan(const int* __restrict__ counts, int* __restrict__ off,
                       int* __restrict__ tile_e, int* __restrict__ tile_v) {
  if (threadIdx.x != 0) return;
  int a = 0, tt = 0;
  for (int e = 0; e < NE; ++e) {
    off[e] = a;
    int c = counts[e];
    int nt = (c + 127) >> 7;
    for (int k = 0; k < nt; ++k) {
      tile_e[tt] = e;
      int v = c - (k << 7);
      tile_v[tt] = v > 128 ? 128 : v;
      ++tt;
    }
    a += nt << 7;
  }
  off[NE] = a;
  for (; tt < NTILES; ++tt) { tile_e[tt] = -1; tile_v[tt] = 0; }
}

// one block (64 threads) per token: claim grouped row, convert row f32->bf16,
// store with 16B-granule XOR swizzle (granule g -> g ^ (row&7) within 128B window)
__global__ void k_gather(const float* __restrict__ x, const int* __restrict__ expert_t,
                         const float* __restrict__ weight_t, const int* __restrict__ off,
                         int* __restrict__ cursors, int* __restrict__ rowtok,
                         float* __restrict__ wrow, u16* __restrict__ xg) {
  const int t = blockIdx.x;
  const int lane = threadIdx.x;
  const int e = expert_t[t];
  int row = 0;
  if (lane == 0) {
    int pos = atomicAdd(cursors + e, 1);
    row = off[e] + pos;
    rowtok[row] = t;
    wrow[row] = weight_t[t];
  }
  row = __shfl(row, 0, 64);
  const int r7 = row & 7;
  const float4* src = (const float4*)(x + (size_t)t * HD);
  uint4* dst = (uint4*)((char*)xg + (size_t)row * (HD * 2));
#pragma unroll
  for (int r = 0; r < 4; ++r) {
    int g = r * 64 + lane;                 // logical 16B granule, 256 per row
    float4 a = src[2 * g], b = src[2 * g + 1];
    dst[(g & ~7) | ((g & 7) ^ r7)] = pk8(a, b);
  }
}

// Fused gate+up GEMM: C tile 128(i) x 128(rows), K=HD, BK=64.
// Swapped operands: A_op = W rows (i), B_op = x rows (m) -> lane owns 4 consecutive i.
__global__ __launch_bounds__(256, 2) void k_gateup(
    const u16* __restrict__ xg, const float* __restrict__ gate_w,
    const float* __restrict__ up_w, const int* __restrict__ tile_e,
    u16* __restrict__ act) {
  __shared__ __align__(16) char lds[49152];  // A 16K | Wg 16K | Wu 16K
  const int e = tile_e[blockIdx.y];
  if (e < 0) return;
  const int i0 = blockIdx.x * 128;
  const int m0 = blockIdx.y * 128;
  const int tid = threadIdx.x;
  const int lane = tid & 63, wv = tid >> 6;
  const int nbase = (wv >> 1) * 64, mbase = (wv & 1) * 64;
  const int l15 = lane & 15, l4 = lane >> 4;
  char* ldsA = lds;
  char* ldsG = lds + 16384;
  char* ldsU = lds + 32768;
  f32x4 accg[4][4], accu[4][4];
#pragma unroll
  for (int i = 0; i < 4; ++i)
#pragma unroll
    for (int j = 0; j < 4; ++j) {
      accg[i][j] = f32x4{0.f, 0.f, 0.f, 0.f};
      accu[i][j] = f32x4{0.f, 0.f, 0.f, 0.f};
    }
  const int trow = tid >> 1, thalf = tid & 1;
  const int wr7 = trow & 7;
  const float* gsrc = gate_w + (size_t)e * ID * HD + (size_t)(i0 + trow) * HD + thalf * 32;
  const float* usrc = up_w   + (size_t)e * ID * HD + (size_t)(i0 + trow) * HD + thalf * 32;

  for (int ks = 0; ks < HD / 64; ++ks) {
    __syncthreads();
    // stage A (xg rows are pre-swizzled -> plain linear copy)
#pragma unroll
    for (int r = 0; r < 4; ++r) {
      int o = (r * 256 + tid) * 16;
      gload_lds16(ldsA + r * 4096 + wv * 1024,
                  (const char*)xg + (size_t)(m0 + (o >> 7)) * (HD * 2) + ks * 128 + (o & 127));
    }
    // stage Wg: 32 f32 per thread -> bf16, XOR-swizzled ds_write
    {
      const float4* s = (const float4*)(gsrc + ks * 64);
      float4 v0 = s[0], v1 = s[1], v2 = s[2], v3 = s[3];
      float4 v4 = s[4], v5 = s[5], v6 = s[6], v7 = s[7];
      *(uint4*)(ldsG + trow * 128 + (((thalf * 4 + 0) ^ wr7) * 16)) = pk8(v0, v1);
      *(uint4*)(ldsG + trow * 128 + (((thalf * 4 + 1) ^ wr7) * 16)) = pk8(v2, v3);
      *(uint4*)(ldsG + trow * 128 + (((thalf * 4 + 2) ^ wr7) * 16)) = pk8(v4, v5);
      *(uint4*)(ldsG + trow * 128 + (((thalf * 4 + 3) ^ wr7) * 16)) = pk8(v6, v7);
    }
    // stage Wu
    {
      const float4* s = (const float4*)(usrc + ks * 64);
      float4 v0 = s[0], v1 = s[1], v2 = s[2], v3 = s[3];
      float4 v4 = s[4], v5 = s[5], v6 = s[6], v7 = s[7];
      *(uint4*)(ldsU + trow * 128 + (((thalf * 4 + 0) ^ wr7) * 16)) = pk8(v0, v1);
      *(uint4*)(ldsU + trow * 128 + (((thalf * 4 + 1) ^ wr7) * 16)) = pk8(v2, v3);
      *(uint4*)(ldsU + trow * 128 + (((thalf * 4 + 2) ^ wr7) * 16)) = pk8(v4, v5);
      *(uint4*)(ldsU + trow * 128 + (((thalf * 4 + 3) ^ wr7) * 16)) = pk8(v6, v7);
    }
    __syncthreads();
#pragma unroll
    for (int kk = 0; kk < 2; ++kk) {
      bf16x8 xa[4], wg[4], wu[4];
#pragma unroll
      for (int f = 0; f < 4; ++f) {
        int rx = mbase + f * 16 + l15;
        int g = kk * 4 + l4;
        xa[f] = *(const bf16x8*)(ldsA + rx * 128 + ((g ^ (rx & 7)) * 16));
        int rw_ = nbase + f * 16 + l15;
        wg[f] = *(const bf16x8*)(ldsG + rw_ * 128 + ((g ^ (rw_ & 7)) * 16));
        wu[f] = *(const bf16x8*)(ldsU + rw_ * 128 + ((g ^ (rw_ & 7)) * 16));
      }
#pragma unroll
      for (int fn = 0; fn < 4; ++fn)
#pragma unroll
        for (int fm = 0; fm < 4; ++fm) {
          accg[fn][fm] = __builtin_amdgcn_mfma_f32_16x16x32_bf16(wg[fn], xa[fm], accg[fn][fm], 0, 0, 0);
          accu[fn][fm] = __builtin_amdgcn_mfma_f32_16x16x32_bf16(wu[fn], xa[fm], accu[fn][fm], 0, 0, 0);
        }
    }
  }
  // epilogue: act = silu(gate)*up -> bf16, stored pre-swizzled
#pragma unroll
  for (int fm = 0; fm < 4; ++fm) {
    int row = m0 + mbase + fm * 16 + l15;
    int r7 = row & 7;
    char* arow = (char*)act + (size_t)row * (ID * 2);
#pragma unroll
    for (int fn = 0; fn < 4; ++fn) {
      f32x4 g4 = accg[fn][fm], u4 = accu[fn][fm];
      float o0 = g4[0] / (1.f + __expf(-g4[0])) * u4[0];
      float o1 = g4[1] / (1.f + __expf(-g4[1])) * u4[1];
      float o2 = g4[2] / (1.f + __expf(-g4[2])) * u4[2];
      float o3 = g4[3] / (1.f + __expf(-g4[3])) * u4[3];
      int ig = i0 + nbase + fn * 16 + l4 * 4;
      int gi = ig >> 3;
      int pgi = (gi & ~7) | ((gi & 7) ^ r7);
      uint2 p;
      p.x = pk2(o0, o1); p.y = pk2(o2, o3);
      *(uint2*)(arow + pgi * 16 + (ig & 7) * 2) = p;
    }
  }
}

// down GEMM: out[t][h] = w_t * act_row . down_w[e][h][:], K=ID, BK=64
__global__ __launch_bounds__(256, 2) void k_down(
    const u16* __restrict__ act, const float* __restrict__ down_w,
    const int* __restrict__ tile_e, const int* __restrict__ tile_v,
    const int* __restrict__ rowtok, const float* __restrict__ wrow,
    float* __restrict__ out) {
  __shared__ __align__(16) char lds[32768];  // act 16K | W 16K
  const int e = tile_e[blockIdx.y];
  if (e < 0) return;
  const int h0 = blockIdx.x * 128;
  const int m0 = blockIdx.y * 128;
  const int tid = threadIdx.x;
  const int lane = tid & 63, wv = tid >> 6;
  const int nbase = (wv >> 1) * 64, mbase = (wv & 1) * 64;
  const int l15 = lane & 15, l4 = lane >> 4;
  char* ldsA = lds;
  char* ldsW = lds + 16384;
  f32x4 acc[4][4];
#pragma unroll
  for (int i = 0; i < 4; ++i)
#pragma unroll
    for (int j = 0; j < 4; ++j) acc[i][j] = f32x4{0.f, 0.f, 0.f, 0.f};
  const int trow = tid >> 1, thalf = tid & 1;
  const int wr7 = trow & 7;
  const float* wsrc = down_w + (size_t)e * HD * ID + (size_t)(h0 + trow) * ID + thalf * 32;

  for (int ks = 0; ks < ID / 64; ++ks) {
    __syncthreads();
#pragma unroll
    for (int r = 0; r < 4; ++r) {
      int o = (r * 256 + tid) * 16;
      gload_lds16(ldsA + r * 4096 + wv * 1024,
                  (const char*)act + (size_t)(m0 + (o >> 7)) * (ID * 2) + ks * 128 + (o & 127));
    }
    {
      const float4* s = (const float4*)(wsrc + ks * 64);
      float4 v0 = s[0], v1 = s[1], v2 = s[2], v3 = s[3];
      float4 v4 = s[4], v5 = s[5], v6 = s[6], v7 = s[7];
      *(uint4*)(ldsW + trow * 128 + (((thalf * 4 + 0) ^ wr7) * 16)) = pk8(v0, v1);
      *(uint4*)(ldsW + trow * 128 + (((thalf * 4 + 1) ^ wr7) * 16)) = pk8(v2, v3);
      *(uint4*)(ldsW + trow * 128 + (((thalf * 4 + 2) ^ wr7) * 16)) = pk8(v4, v5);
      *(uint4*)(ldsW + trow * 128 + (((thalf * 4 + 3) ^ wr7) * 16)) = pk8(v6, v7);
    }
    __syncthreads();
#pragma unroll
    for (int kk = 0; kk < 2; ++kk) {
      bf16x8 xa[4], wf[4];
#pragma unroll
      for (int f = 0; f < 4; ++f) {
        int rx = mbase + f * 16 + l15;
        int g = kk * 4 + l4;
        xa[f] = *(const bf16x8*)(ldsA + rx * 128 + ((g ^ (rx & 7)) * 16));
        int rw_ = nbase + f * 16 + l15;
        wf[f] = *(const bf16x8*)(ldsW + rw_ * 128 + ((g ^ (rw_ & 7)) * 16));
      }
#pragma unroll
      for (int fn = 0; fn < 4; ++fn)
#pragma unroll
        for (int fm = 0; fm < 4; ++fm)
          acc[fn][fm] = __builtin_amdgcn_mfma_f32_16x16x32_bf16(wf[fn], xa[fm], acc[fn][fm], 0, 0, 0);
    }
  }
  const int valid = tile_v[blockIdx.y];
#pragma unroll
  for (int fm = 0; fm < 4; ++fm) {
    int ml = mbase + fm * 16 + l15;
    if (ml < valid) {
      int t = rowtok[m0 + ml];
      float wgt = wrow[m0 + ml];
      float* orow = out + (size_t)t * HD + h0 + nbase;
#pragma unroll
      for (int fn = 0; fn < 4; ++fn) {
        f32x4 v = acc[fn][fm];
        float4 o;
        o.x = v[0] * wgt; o.y = v[1] * wgt; o.z = v[2] * wgt; o.w = v[3] * wgt;
        *(float4*)(orow + fn * 16 + l4 * 4) = o;
      }
    }
  }
}

extern "C" void kernel_launch(void* const* d_in, const int* in_sizes, int n_in,
                              void* d_out, int out_size, void* d_ws, size_t ws_size,
                              hipStream_t stream) {
  const float* x  = (const float*)d_in[0];
  const float* rw = (const float*)d_in[1];
  const float* gw = (const float*)d_in[2];
  const float* uw = (const float*)d_in[3];
  const float* dw = (const float*)d_in[4];
  float* out = (float*)d_out;
  char* ws = (char*)d_ws;

  int*   counts   = (int*)(ws + 0);
  int*   cursors  = (int*)(ws + 64);
  int*   off      = (int*)(ws + 128);
  int*   tile_e   = (int*)(ws + 256);
  int*   tile_v   = (int*)(ws + 512);
  int*   expert_t = (int*)(ws + 1024);
  float* weight_t = (float*)(ws + 17408);
  int*   rowtok   = (int*)(ws + 33792);
  float* wrow     = (float*)(ws + 54272);
  u16*   xg       = (u16*)(ws + 74752);
  u16*   act      = (u16*)(ws + 74752 + (size_t)GMAX * HD * 2);

  k_init<<<1, 64, 0, stream>>>(counts, cursors);
  k_router<<<TOK / 4, 256, 0, stream>>>(x, rw, counts, expert_t, weight_t);
  k_scan<<<1, 64, 0, stream>>>(counts, off, tile_e, tile_v);
  k_gather<<<TOK, 64, 0, stream>>>(x, expert_t, weight_t, off, cursors, rowtok, wrow, xg);
  k_gateup<<<dim3(ID / 128, NTILES), 256, 0, stream>>>(xg, gw, uw, tile_e, act);
  k_down<<<dim3(HD / 128, NTILES), 256, 0, stream>>>(act, dw, tile_e, tile_v, rowtok, wrow, out);
}

// Round 9
// 527.605 us; speedup vs baseline: 1.2455x; 1.2455x over previous
//
#include <hip/hip_runtime.h>
#include <stdint.h>

#define TOK 4096
#define HD 2048
#define ID 1408
#define NE 8
#define GMAX 5120
#define NTILES 40

// workspace layout (bytes)
#define XG_OFF   74752ULL
#define XG_BYTES (5120ULL * 2048 * 2)
#define ACT_OFF  (XG_OFF + XG_BYTES)
#define ACT_BYTES (5120ULL * 1408 * 2)
#define GWB_OFF  (ACT_OFF + ACT_BYTES)
#define W_BYTES  (8ULL * 1408 * 2048 * 2)
#define UWB_OFF  (GWB_OFF + W_BYTES)
#define DWB_OFF  (UWB_OFF + W_BYTES)
#define WS_NEED  (DWB_OFF + W_BYTES)

typedef unsigned short u16;
typedef unsigned int u32;
typedef __attribute__((ext_vector_type(8))) short bf16x8;
typedef __attribute__((ext_vector_type(4))) float f32x4;

__device__ inline u16 f2bf(float f) {
  u32 u = __builtin_bit_cast(u32, f);
  u += 0x7fff + ((u >> 16) & 1);   // RNE
  return (u16)(u >> 16);
}
__device__ inline u32 pk2(float a, float b) {
  return (u32)f2bf(a) | ((u32)f2bf(b) << 16);
}
__device__ inline uint4 pk8(const float4& a, const float4& b) {
  uint4 r;
  r.x = pk2(a.x, a.y); r.y = pk2(a.z, a.w);
  r.z = pk2(b.x, b.y); r.w = pk2(b.z, b.w);
  return r;
}
__device__ inline void gload_lds16(void* lds, const void* g) {
  __builtin_amdgcn_global_load_lds(
      (const __attribute__((address_space(1))) u32*)g,
      (__attribute__((address_space(3))) u32*)lds, 16, 0, 0);
}

__global__ void k_init(int* counts, int* cursors) {
  if (threadIdx.x < NE) { counts[threadIdx.x] = 0; cursors[threadIdx.x] = 0; }
}

// f32 -> bf16 row cast with 16B-granule XOR swizzle (same layout as xg/act):
// granule g of row stored at (g&~7)|((g&7)^(row&7)).  one block per row.
__global__ void k_cast(const float* __restrict__ src, u16* __restrict__ dst, int K) {
  const int row = blockIdx.x;
  const int g = threadIdx.x;
  const int ng = K >> 3;
  if (g < ng) {
    const float4* s = (const float4*)(src + (size_t)row * K + g * 8);
    float4 a = s[0], b = s[1];
    uint4* d = (uint4*)((char*)dst + (size_t)row * K * 2);
    d[(g & ~7) | ((g & 7) ^ (row & 7))] = pk8(a, b);
  }
}

__global__ void k_router(const float* __restrict__ x, const float* __restrict__ rw,
                         int* __restrict__ counts, int* __restrict__ expert_t,
                         float* __restrict__ weight_t) {
  const int lane = threadIdx.x & 63;
  const int t = blockIdx.x * 4 + (threadIdx.x >> 6);
  const float4* xr = (const float4*)(x + (size_t)t * HD);
  float acc[NE];
#pragma unroll
  for (int e = 0; e < NE; ++e) acc[e] = 0.f;
#pragma unroll
  for (int it = 0; it < HD / 256; ++it) {
    float4 xv = xr[it * 64 + lane];
#pragma unroll
    for (int e = 0; e < NE; ++e) {
      float4 wv = ((const float4*)(rw + e * HD))[it * 64 + lane];
      acc[e] += xv.x * wv.x + xv.y * wv.y + xv.z * wv.z + xv.w * wv.w;
    }
  }
#pragma unroll
  for (int e = 0; e < NE; ++e) {
#pragma unroll
    for (int off = 32; off > 0; off >>= 1) acc[e] += __shfl_xor(acc[e], off, 64);
  }
  if (lane == 0) {
    float v0 = -1e30f, v1 = -1e30f; int ie = 0;
#pragma unroll
    for (int e = 0; e < NE; ++e) {
      float v = acc[e];
      if (v > v0) { v1 = v0; v0 = v; ie = e; }
      else if (v > v1) { v1 = v; }
    }
    expert_t[t] = ie;
    weight_t[t] = 1.f / (1.f + __expf(v1 - v0));
    atomicAdd(counts + ie, 1);
  }
}

__global__ void k_scan(const int* __restrict__ counts, int* __restrict__ off,
                       int* __restrict__ tile_e, int* __restrict__ tile_v) {
  if (threadIdx.x != 0) return;
  int a = 0, tt = 0;
  for (int e = 0; e < NE; ++e) {
    off[e] = a;
    int c = counts[e];
    int nt = (c + 127) >> 7;
    for (int k = 0; k < nt; ++k) {
      tile_e[tt] = e;
      int v = c - (k << 7);
      tile_v[tt] = v > 128 ? 128 : v;
      ++tt;
    }
    a += nt << 7;
  }
  off[NE] = a;
  for (; tt < NTILES; ++tt) { tile_e[tt] = -1; tile_v[tt] = 0; }
}

__global__ void k_gather(const float* __restrict__ x, const int* __restrict__ expert_t,
                         const float* __restrict__ weight_t, const int* __restrict__ off,
                         int* __restrict__ cursors, int* __restrict__ rowtok,
                         float* __restrict__ wrow, u16* __restrict__ xg) {
  const int t = blockIdx.x;
  const int lane = threadIdx.x;
  const int e = expert_t[t];
  int row = 0;
  if (lane == 0) {
    int pos = atomicAdd(cursors + e, 1);
    row = off[e] + pos;
    rowtok[row] = t;
    wrow[row] = weight_t[t];
  }
  row = __shfl(row, 0, 64);
  const int r7 = row & 7;
  const float4* src = (const float4*)(x + (size_t)t * HD);
  uint4* dst = (uint4*)((char*)xg + (size_t)row * (HD * 2));
#pragma unroll
  for (int r = 0; r < 4; ++r) {
    int g = r * 64 + lane;
    float4 a = src[2 * g], b = src[2 * g + 1];
    dst[(g & ~7) | ((g & 7) ^ r7)] = pk8(a, b);
  }
}

// ---- bf16-weight path: all staging via global_load_lds (pre-swizzled sources) ----
__global__ __launch_bounds__(256, 2) void k_gateup_b(
    const u16* __restrict__ xg, const u16* __restrict__ gwb,
    const u16* __restrict__ uwb, const int* __restrict__ tile_e,
    u16* __restrict__ act) {
  __shared__ __align__(16) char lds[49152];  // A 16K | Wg 16K | Wu 16K
  const int e = tile_e[blockIdx.y];
  if (e < 0) return;
  const int i0 = blockIdx.x * 128;
  const int m0 = blockIdx.y * 128;
  const int tid = threadIdx.x;
  const int lane = tid & 63, wv = tid >> 6;
  const int nbase = (wv >> 1) * 64, mbase = (wv & 1) * 64;
  const int l15 = lane & 15, l4 = lane >> 4;
  char* ldsA = lds;
  char* ldsG = lds + 16384;
  char* ldsU = lds + 32768;
  f32x4 accg[4][4], accu[4][4];
#pragma unroll
  for (int i = 0; i < 4; ++i)
#pragma unroll
    for (int j = 0; j < 4; ++j) {
      accg[i][j] = f32x4{0.f, 0.f, 0.f, 0.f};
      accu[i][j] = f32x4{0.f, 0.f, 0.f, 0.f};
    }
  const char* asrc = (const char*)xg  + (size_t)m0 * (HD * 2);
  const char* gsrc = (const char*)gwb + (size_t)(e * ID + i0) * (HD * 2);
  const char* usrc = (const char*)uwb + (size_t)(e * ID + i0) * (HD * 2);

  for (int ks = 0; ks < HD / 64; ++ks) {
    __syncthreads();
#pragma unroll
    for (int r = 0; r < 4; ++r) {
      int o = (r * 256 + tid) * 16;
      size_t rowoff = (size_t)(o >> 7) * (HD * 2) + ks * 128 + (o & 127);
      char* ldst = lds + r * 4096 + wv * 1024;
      gload_lds16(ldst,           asrc + rowoff);
      gload_lds16(ldst + 16384,   gsrc + rowoff);
      gload_lds16(ldst + 32768,   usrc + rowoff);
    }
    __syncthreads();
#pragma unroll
    for (int kk = 0; kk < 2; ++kk) {
      bf16x8 xa[4], wg[4], wu[4];
#pragma unroll
      for (int f = 0; f < 4; ++f) {
        int rx = mbase + f * 16 + l15;
        int g = kk * 4 + l4;
        xa[f] = *(const bf16x8*)(ldsA + rx * 128 + ((g ^ (rx & 7)) * 16));
        int rw_ = nbase + f * 16 + l15;
        wg[f] = *(const bf16x8*)(ldsG + rw_ * 128 + ((g ^ (rw_ & 7)) * 16));
        wu[f] = *(const bf16x8*)(ldsU + rw_ * 128 + ((g ^ (rw_ & 7)) * 16));
      }
#pragma unroll
      for (int fn = 0; fn < 4; ++fn)
#pragma unroll
        for (int fm = 0; fm < 4; ++fm) {
          accg[fn][fm] = __builtin_amdgcn_mfma_f32_16x16x32_bf16(wg[fn], xa[fm], accg[fn][fm], 0, 0, 0);
          accu[fn][fm] = __builtin_amdgcn_mfma_f32_16x16x32_bf16(wu[fn], xa[fm], accu[fn][fm], 0, 0, 0);
        }
    }
  }
#pragma unroll
  for (int fm = 0; fm < 4; ++fm) {
    int row = m0 + mbase + fm * 16 + l15;
    int r7 = row & 7;
    char* arow = (char*)act + (size_t)row * (ID * 2);
#pragma unroll
    for (int fn = 0; fn < 4; ++fn) {
      f32x4 g4 = accg[fn][fm], u4 = accu[fn][fm];
      float o0 = g4[0] / (1.f + __expf(-g4[0])) * u4[0];
      float o1 = g4[1] / (1.f + __expf(-g4[1])) * u4[1];
      float o2 = g4[2] / (1.f + __expf(-g4[2])) * u4[2];
      float o3 = g4[3] / (1.f + __expf(-g4[3])) * u4[3];
      int ig = i0 + nbase + fn * 16 + l4 * 4;
      int gi = ig >> 3;
      int pgi = (gi & ~7) | ((gi & 7) ^ r7);
      uint2 p;
      p.x = pk2(o0, o1); p.y = pk2(o2, o3);
      *(uint2*)(arow + pgi * 16 + (ig & 7) * 2) = p;
    }
  }
}

__global__ __launch_bounds__(256, 2) void k_down_b(
    const u16* __restrict__ act, const u16* __restrict__ dwb,
    const int* __restrict__ tile_e, const int* __restrict__ tile_v,
    const int* __restrict__ rowtok, const float* __restrict__ wrow,
    float* __restrict__ out) {
  __shared__ __align__(16) char lds[32768];  // act 16K | W 16K
  const int e = tile_e[blockIdx.y];
  if (e < 0) return;
  const int h0 = blockIdx.x * 128;
  const int m0 = blockIdx.y * 128;
  const int tid = threadIdx.x;
  const int lane = tid & 63, wv = tid >> 6;
  const int nbase = (wv >> 1) * 64, mbase = (wv & 1) * 64;
  const int l15 = lane & 15, l4 = lane >> 4;
  char* ldsA = lds;
  char* ldsW = lds + 16384;
  f32x4 acc[4][4];
#pragma unroll
  for (int i = 0; i < 4; ++i)
#pragma unroll
    for (int j = 0; j < 4; ++j) acc[i][j] = f32x4{0.f, 0.f, 0.f, 0.f};
  const char* asrc = (const char*)act + (size_t)m0 * (ID * 2);
  const char* wsrc = (const char*)dwb + (size_t)(e * HD + h0) * (ID * 2);

  for (int ks = 0; ks < ID / 64; ++ks) {
    __syncthreads();
#pragma unroll
    for (int r = 0; r < 4; ++r) {
      int o = (r * 256 + tid) * 16;
      size_t rowoff = (size_t)(o >> 7) * (ID * 2) + ks * 128 + (o & 127);
      char* ldst = lds + r * 4096 + wv * 1024;
      gload_lds16(ldst,         asrc + rowoff);
      gload_lds16(ldst + 16384, wsrc + rowoff);
    }
    __syncthreads();
#pragma unroll
    for (int kk = 0; kk < 2; ++kk) {
      bf16x8 xa[4], wf[4];
#pragma unroll
      for (int f = 0; f < 4; ++f) {
        int rx = mbase + f * 16 + l15;
        int g = kk * 4 + l4;
        xa[f] = *(const bf16x8*)(ldsA + rx * 128 + ((g ^ (rx & 7)) * 16));
        int rw_ = nbase + f * 16 + l15;
        wf[f] = *(const bf16x8*)(ldsW + rw_ * 128 + ((g ^ (rw_ & 7)) * 16));
      }
#pragma unroll
      for (int fn = 0; fn < 4; ++fn)
#pragma unroll
        for (int fm = 0; fm < 4; ++fm)
          acc[fn][fm] = __builtin_amdgcn_mfma_f32_16x16x32_bf16(wf[fn], xa[fm], acc[fn][fm], 0, 0, 0);
    }
  }
  const int valid = tile_v[blockIdx.y];
#pragma unroll
  for (int fm = 0; fm < 4; ++fm) {
    int ml = mbase + fm * 16 + l15;
    if (ml < valid) {
      int t = rowtok[m0 + ml];
      float wgt = wrow[m0 + ml];
      float* orow = out + (size_t)t * HD + h0 + nbase;
#pragma unroll
      for (int fn = 0; fn < 4; ++fn) {
        f32x4 v = acc[fn][fm];
        float4 o;
        o.x = v[0] * wgt; o.y = v[1] * wgt; o.z = v[2] * wgt; o.w = v[3] * wgt;
        *(float4*)(orow + fn * 16 + l4 * 4) = o;
      }
    }
  }
}

// ---- f32-weight fallback path (round-7 kernels, used only if ws too small) ----
__global__ __launch_bounds__(256, 2) void k_gateup_f(
    const u16* __restrict__ xg, const float* __restrict__ gate_w,
    const float* __restrict__ up_w, const int* __restrict__ tile_e,
    u16* __restrict__ act) {
  __shared__ __align__(16) char lds[49152];
  const int e = tile_e[blockIdx.y];
  if (e < 0) return;
  const int i0 = blockIdx.x * 128;
  const int m0 = blockIdx.y * 128;
  const int tid = threadIdx.x;
  const int lane = tid & 63, wv = tid >> 6;
  const int nbase = (wv >> 1) * 64, mbase = (wv & 1) * 64;
  const int l15 = lane & 15, l4 = lane >> 4;
  char* ldsA = lds;
  char* ldsG = lds + 16384;
  char* ldsU = lds + 32768;
  f32x4 accg[4][4], accu[4][4];
#pragma unroll
  for (int i = 0; i < 4; ++i)
#pragma unroll
    for (int j = 0; j < 4; ++j) {
      accg[i][j] = f32x4{0.f, 0.f, 0.f, 0.f};
      accu[i][j] = f32x4{0.f, 0.f, 0.f, 0.f};
    }
  const int trow = tid >> 1, thalf = tid & 1;
  const int wr7 = trow & 7;
  const float* gsrc = gate_w + (size_t)e * ID * HD + (size_t)(i0 + trow) * HD + thalf * 32;
  const float* usrc = up_w   + (size_t)e * ID * HD + (size_t)(i0 + trow) * HD + thalf * 32;
  for (int ks = 0; ks < HD / 64; ++ks) {
    __syncthreads();
#pragma unroll
    for (int r = 0; r < 4; ++r) {
      int o = (r * 256 + tid) * 16;
      gload_lds16(ldsA + r * 4096 + wv * 1024,
                  (const char*)xg + (size_t)(m0 + (o >> 7)) * (HD * 2) + ks * 128 + (o & 127));
    }
    {
      const float4* s = (const float4*)(gsrc + ks * 64);
      float4 v0 = s[0], v1 = s[1], v2 = s[2], v3 = s[3];
      float4 v4 = s[4], v5 = s[5], v6 = s[6], v7 = s[7];
      *(uint4*)(ldsG + trow * 128 + (((thalf * 4 + 0) ^ wr7) * 16)) = pk8(v0, v1);
      *(uint4*)(ldsG + trow * 128 + (((thalf * 4 + 1) ^ wr7) * 16)) = pk8(v2, v3);
      *(uint4*)(ldsG + trow * 128 + (((thalf * 4 + 2) ^ wr7) * 16)) = pk8(v4, v5);
      *(uint4*)(ldsG + trow * 128 + (((thalf * 4 + 3) ^ wr7) * 16)) = pk8(v6, v7);
    }
    {
      const float4* s = (const float4*)(usrc + ks * 64);
      float4 v0 = s[0], v1 = s[1], v2 = s[2], v3 = s[3];
      float4 v4 = s[4], v5 = s[5], v6 = s[6], v7 = s[7];
      *(uint4*)(ldsU + trow * 128 + (((thalf * 4 + 0) ^ wr7) * 16)) = pk8(v0, v1);
      *(uint4*)(ldsU + trow * 128 + (((thalf * 4 + 1) ^ wr7) * 16)) = pk8(v2, v3);
      *(uint4*)(ldsU + trow * 128 + (((thalf * 4 + 2) ^ wr7) * 16)) = pk8(v4, v5);
      *(uint4*)(ldsU + trow * 128 + (((thalf * 4 + 3) ^ wr7) * 16)) = pk8(v6, v7);
    }
    __syncthreads();
#pragma unroll
    for (int kk = 0; kk < 2; ++kk) {
      bf16x8 xa[4], wg[4], wu[4];
#pragma unroll
      for (int f = 0; f < 4; ++f) {
        int rx = mbase + f * 16 + l15;
        int g = kk * 4 + l4;
        xa[f] = *(const bf16x8*)(ldsA + rx * 128 + ((g ^ (rx & 7)) * 16));
        int rw_ = nbase + f * 16 + l15;
        wg[f] = *(const bf16x8*)(ldsG + rw_ * 128 + ((g ^ (rw_ & 7)) * 16));
        wu[f] = *(const bf16x8*)(ldsU + rw_ * 128 + ((g ^ (rw_ & 7)) * 16));
      }
#pragma unroll
      for (int fn = 0; fn < 4; ++fn)
#pragma unroll
        for (int fm = 0; fm < 4; ++fm) {
          accg[fn][fm] = __builtin_amdgcn_mfma_f32_16x16x32_bf16(wg[fn], xa[fm], accg[fn][fm], 0, 0, 0);
          accu[fn][fm] = __builtin_amdgcn_mfma_f32_16x16x32_bf16(wu[fn], xa[fm], accu[fn][fm], 0, 0, 0);
        }
    }
  }
#pragma unroll
  for (int fm = 0; fm < 4; ++fm) {
    int row = m0 + mbase + fm * 16 + l15;
    int r7 = row & 7;
    char* arow = (char*)act + (size_t)row * (ID * 2);
#pragma unroll
    for (int fn = 0; fn < 4; ++fn) {
      f32x4 g4 = accg[fn][fm], u4 = accu[fn][fm];
      float o0 = g4[0] / (1.f + __expf(-g4[0])) * u4[0];
      float o1 = g4[1] / (1.f + __expf(-g4[1])) * u4[1];
      float o2 = g4[2] / (1.f + __expf(-g4[2])) * u4[2];
      float o3 = g4[3] / (1.f + __expf(-g4[3])) * u4[3];
      int ig = i0 + nbase + fn * 16 + l4 * 4;
      int gi = ig >> 3;
      int pgi = (gi & ~7) | ((gi & 7) ^ r7);
      uint2 p;
      p.x = pk2(o0, o1); p.y = pk2(o2, o3);
      *(uint2*)(arow + pgi * 16 + (ig & 7) * 2) = p;
    }
  }
}

__global__ __launch_bounds__(256, 2) void k_down_f(
    const u16* __restrict__ act, const float* __restrict__ down_w,
    const int* __restrict__ tile_e, const int* __restrict__ tile_v,
    const int* __restrict__ rowtok, const float* __restrict__ wrow,
    float* __restrict__ out) {
  __shared__ __align__(16) char lds[32768];
  const int e = tile_e[blockIdx.y];
  if (e < 0) return;
  const int h0 = blockIdx.x * 128;
  const int m0 = blockIdx.y * 128;
  const int tid = threadIdx.x;
  const int lane = tid & 63, wv = tid >> 6;
  const int nbase = (wv >> 1) * 64, mbase = (wv & 1) * 64;
  const int l15 = lane & 15, l4 = lane >> 4;
  char* ldsA = lds;
  char* ldsW = lds + 16384;
  f32x4 acc[4][4];
#pragma unroll
  for (int i = 0; i < 4; ++i)
#pragma unroll
    for (int j = 0; j < 4; ++j) acc[i][j] = f32x4{0.f, 0.f, 0.f, 0.f};
  const int trow = tid >> 1, thalf = tid & 1;
  const int wr7 = trow & 7;
  const float* wsrc = down_w + (size_t)e * HD * ID + (size_t)(h0 + trow) * ID + thalf * 32;
  for (int ks = 0; ks < ID / 64; ++ks) {
    __syncthreads();
#pragma unroll
    for (int r = 0; r < 4; ++r) {
      int o = (r * 256 + tid) * 16;
      gload_lds16(ldsA + r * 4096 + wv * 1024,
                  (const char*)act + (size_t)(m0 + (o >> 7)) * (ID * 2) + ks * 128 + (o & 127));
    }
    {
      const float4* s = (const float4*)(wsrc + ks * 64);
      float4 v0 = s[0], v1 = s[1], v2 = s[2], v3 = s[3];
      float4 v4 = s[4], v5 = s[5], v6 = s[6], v7 = s[7];
      *(uint4*)(ldsW + trow * 128 + (((thalf * 4 + 0) ^ wr7) * 16)) = pk8(v0, v1);
      *(uint4*)(ldsW + trow * 128 + (((thalf * 4 + 1) ^ wr7) * 16)) = pk8(v2, v3);
      *(uint4*)(ldsW + trow * 128 + (((thalf * 4 + 2) ^ wr7) * 16)) = pk8(v4, v5);
      *(uint4*)(ldsW + trow * 128 + (((thalf * 4 + 3) ^ wr7) * 16)) = pk8(v6, v7);
    }
    __syncthreads();
#pragma unroll
    for (int kk = 0; kk < 2; ++kk) {
      bf16x8 xa[4], wf[4];
#pragma unroll
      for (int f = 0; f < 4; ++f) {
        int rx = mbase + f * 16 + l15;
        int g = kk * 4 + l4;
        xa[f] = *(const bf16x8*)(ldsA + rx * 128 + ((g ^ (rx & 7)) * 16));
        int rw_ = nbase + f * 16 + l15;
        wf[f] = *(const bf16x8*)(ldsW + rw_ * 128 + ((g ^ (rw_ & 7)) * 16));
      }
#pragma unroll
      for (int fn = 0; fn < 4; ++fn)
#pragma unroll
        for (int fm = 0; fm < 4; ++fm)
          acc[fn][fm] = __builtin_amdgcn_mfma_f32_16x16x32_bf16(wf[fn], xa[fm], acc[fn][fm], 0, 0, 0);
    }
  }
  const int valid = tile_v[blockIdx.y];
#pragma unroll
  for (int fm = 0; fm < 4; ++fm) {
    int ml = mbase + fm * 16 + l15;
    if (ml < valid) {
      int t = rowtok[m0 + ml];
      float wgt = wrow[m0 + ml];
      float* orow = out + (size_t)t * HD + h0 + nbase;
#pragma unroll
      for (int fn = 0; fn < 4; ++fn) {
        f32x4 v = acc[fn][fm];
        float4 o;
        o.x = v[0] * wgt; o.y = v[1] * wgt; o.z = v[2] * wgt; o.w = v[3] * wgt;
        *(float4*)(orow + fn * 16 + l4 * 4) = o;
      }
    }
  }
}

extern "C" void kernel_launch(void* const* d_in, const int* in_sizes, int n_in,
                              void* d_out, int out_size, void* d_ws, size_t ws_size,
                              hipStream_t stream) {
  const float* x  = (const float*)d_in[0];
  const float* rw = (const float*)d_in[1];
  const float* gw = (const float*)d_in[2];
  const float* uw = (const float*)d_in[3];
  const float* dw = (const float*)d_in[4];
  float* out = (float*)d_out;
  char* ws = (char*)d_ws;

  int*   counts   = (int*)(ws + 0);
  int*   cursors  = (int*)(ws + 64);
  int*   off      = (int*)(ws + 128);
  int*   tile_e   = (int*)(ws + 256);
  int*   tile_v   = (int*)(ws + 512);
  int*   expert_t = (int*)(ws + 1024);
  float* weight_t = (float*)(ws + 17408);
  int*   rowtok   = (int*)(ws + 33792);
  float* wrow     = (float*)(ws + 54272);
  u16*   xg       = (u16*)(ws + XG_OFF);
  u16*   act      = (u16*)(ws + ACT_OFF);
  u16*   gwb      = (u16*)(ws + GWB_OFF);
  u16*   uwb      = (u16*)(ws + UWB_OFF);
  u16*   dwb      = (u16*)(ws + DWB_OFF);

  const bool big = ws_size >= WS_NEED;

  k_init<<<1, 64, 0, stream>>>(counts, cursors);
  if (big) {
    k_cast<<<NE * ID, 256, 0, stream>>>(gw, gwb, HD);
    k_cast<<<NE * ID, 256, 0, stream>>>(uw, uwb, HD);
    k_cast<<<NE * HD, 256, 0, stream>>>(dw, dwb, ID);
  }
  k_router<<<TOK / 4, 256, 0, stream>>>(x, rw, counts, expert_t, weight_t);
  k_scan<<<1, 64, 0, stream>>>(counts, off, tile_e, tile_v);
  k_gather<<<TOK, 64, 0, stream>>>(x, expert_t, weight_t, off, cursors, rowtok, wrow, xg);
  if (big) {
    k_gateup_b<<<dim3(ID / 128, NTILES), 256, 0, stream>>>(xg, gwb, uwb, tile_e, act);
    k_down_b<<<dim3(HD / 128, NTILES), 256, 0, stream>>>(act, dwb, tile_e, tile_v, rowtok, wrow, out);
  } else {
    k_gateup_f<<<dim3(ID / 128, NTILES), 256, 0, stream>>>(xg, gw, uw, tile_e, act);
    k_down_f<<<dim3(HD / 128, NTILES), 256, 0, stream>>>(act, dw, tile_e, tile_v, rowtok, wrow, out);
  }
}